// Round 2
// baseline (2914.251 us; speedup 1.0000x reference)
//
#include <hip/hip_runtime.h>

typedef unsigned short u16;
typedef unsigned int u32;
typedef __attribute__((ext_vector_type(8))) _Float16 half8;
typedef __attribute__((ext_vector_type(4))) float f32x4;

#define B_ 32
#define T_ 512
// ws layout (bytes)
#define OFF_WP   ((size_t)0)            // [kt16][nt64][lane64][j8] f16 : 1MB
#define OFF_UFP  ((size_t)1 << 20)      // [kt16][nt32][lane64][j8] f16 : 512KB
#define OFF_UBP  (((size_t)1 << 20) + ((size_t)512 << 10))
#define OFF_APK  ((size_t)2 << 20)      // A-frags for gemm; REUSED after gemm:
#define OFF_FLAG OFF_APK                //   16 flags (zeroed before rnn)
#define OFF_XB   (OFF_APK + 4096)       //   h-exchange: 2 parity x 4 groups x 16x512 f16 = 128KB
#define OFF_XP   ((size_t)18 << 20)     // [t512][dir2][b32][h512] f16 : 32MB
#define OUT_ELEMS ((size_t)B_ * T_ * 1024)

__device__ __forceinline__ u16 f2h(float f) {
  _Float16 h = (_Float16)f; u16 r; __builtin_memcpy(&r, &h, 2); return r;
}
__device__ __forceinline__ float h2f(u16 b) {
  _Float16 h; __builtin_memcpy(&h, &b, 2); return (float)h;
}
__device__ __forceinline__ u32 pkh(float a, float b) {
  return (u32)f2h(a) | ((u32)f2h(b) << 16);
}
__device__ __forceinline__ float tanh_fast(float s) {
  float e2 = __expf(2.f * s);
  return 1.f - 2.f * __builtin_amdgcn_rcpf(e2 + 1.f);
}

// ---------------- P1: pack Wf|Wb (N=1024) and Uf, Ub (N=512) into B-frag order
__global__ void pack_WU(const float* __restrict__ Wf, const float* __restrict__ Wb,
                        const float* __restrict__ Uf, const float* __restrict__ Ub,
                        u16* __restrict__ Wp, u16* __restrict__ Ufp, u16* __restrict__ Ubp) {
  int tid = blockIdx.x * 256 + threadIdx.x;  // 131072 total
  const float* src; u16* dst; int NT, k, n0;
  if (tid < 65536) {
    k = tid >> 7; n0 = (tid & 127) * 8;
    src = (n0 < 512) ? (Wf + (size_t)k * 512 + n0) : (Wb + (size_t)k * 512 + (n0 - 512));
    dst = Wp; NT = 64;
  } else if (tid < 98304) {
    int q = tid - 65536; k = q >> 6; n0 = (q & 63) * 8;
    src = Uf + (size_t)k * 512 + n0; dst = Ufp; NT = 32;
  } else {
    int q = tid - 98304; k = q >> 6; n0 = (q & 63) * 8;
    src = Ub + (size_t)k * 512 + n0; dst = Ubp; NT = 32;
  }
  float4 v0 = *(const float4*)src;
  float4 v1 = *(const float4*)(src + 4);
  float v[8] = {v0.x, v0.y, v0.z, v0.w, v1.x, v1.y, v1.z, v1.w};
  int kt = k >> 5, lhi = (k >> 3) & 3, jj = k & 7;
#pragma unroll
  for (int j = 0; j < 8; ++j) {
    int n = n0 + j, nt = n >> 4, llo = n & 15;
    dst[((size_t)(kt * NT + nt) * 64 + lhi * 16 + llo) * 8 + jj] = f2h(v[j]);
  }
}

// ---------------- P2: gather emb rows, convert f16, pack in A-frag order
__global__ void gather_pack_A(const int* __restrict__ x, const float* __restrict__ emb,
                              u16* __restrict__ Apk) {
  int tid = blockIdx.x * 256 + threadIdx.x;  // 1048576 total
  int l = tid & 63, kt = (tid >> 6) & 15, mt = tid >> 10;
  int m = mt * 16 + (l & 15);
  int tok = x[m];
  int k0 = kt * 32 + ((l >> 4) << 3);
  const float* src = emb + (size_t)tok * 512 + k0;
  float4 v0 = *(const float4*)src;
  float4 v1 = *(const float4*)(src + 4);
  uint4 o;
  o.x = pkh(v0.x, v0.y); o.y = pkh(v0.z, v0.w);
  o.z = pkh(v1.x, v1.y); o.w = pkh(v1.z, v1.w);
  *(uint4*)(Apk + (size_t)tid * 8) = o;
}

// ---------------- G: fragment-direct GEMM  xp[t][dir][b][h] = (emb[x] @ Wcat + bias)
__launch_bounds__(256)
__global__ void gemm_xp(const u16* __restrict__ Apk, const u16* __restrict__ Wp,
                        const float* __restrict__ bf, const float* __restrict__ bb,
                        u16* __restrict__ xp) {
  int bid = blockIdx.x;            // 1024 = 128 (M) x 8 (N)
  int bm = bid >> 3, bn = bid & 7;
  int tid = threadIdx.x, l = tid & 63, wid = tid >> 6;
  int wm = wid >> 1, wn = wid & 1;
  int mt0 = bm * 8 + wm * 4;
  int nt0 = bn * 8 + wn * 4;
  const half8* Ap = (const half8*)Apk;
  const half8* Bp = (const half8*)Wp;
  f32x4 acc[4][4] = {};
#pragma unroll 2
  for (int kt = 0; kt < 16; ++kt) {
    half8 a[4], b[4];
#pragma unroll
    for (int i = 0; i < 4; ++i) a[i] = Ap[(size_t)((mt0 + i) * 16 + kt) * 64 + l];
#pragma unroll
    for (int j = 0; j < 4; ++j) b[j] = Bp[(size_t)(kt * 64 + nt0 + j) * 64 + l];
#pragma unroll
    for (int i = 0; i < 4; ++i)
#pragma unroll
      for (int j = 0; j < 4; ++j)
        acc[i][j] = __builtin_amdgcn_mfma_f32_16x16x32_f16(a[i], b[j], acc[i][j], 0, 0, 0);
  }
  int lr = l >> 4, lc = l & 15;
#pragma unroll
  for (int j = 0; j < 4; ++j) {
    int col = (nt0 + j) * 16 + lc;
    int dir = col >> 9, h = col & 511;
    float bias = dir ? bb[h] : bf[h];
#pragma unroll
    for (int i = 0; i < 4; ++i) {
#pragma unroll
      for (int r = 0; r < 4; ++r) {
        int m = (mt0 + i) * 16 + lr * 4 + r;
        int b = m >> 9, t = m & 511;
        xp[((size_t)(t * 2 + dir) * 32 + b) * 512 + h] = f2h(acc[i][j][r] + bias);
      }
    }
  }
}

__global__ void zero_flags(int* f) { f[threadIdx.x] = 0; }

// ---------------- R: cooperative RNN scans.
// 4 groups (dir x batch-half) x 4 col-slices of 128. U register-resident
// (16 B-frags/wave = 64 VGPR). Per step: MFMA 16x128 slice -> tanh ->
// exchange h-slices via double-buffered global xb + agent-scope flags.
__launch_bounds__(512, 1)
__global__ void rnn_scan2(const u16* __restrict__ xp, const u16* __restrict__ Ufp,
                          const u16* __restrict__ Ubp, const float* __restrict__ hidden_f,
                          const float* __restrict__ hidden_b, float* __restrict__ out,
                          float* __restrict__ state_f, float* __restrict__ state_b,
                          int* __restrict__ flags, u16* __restrict__ xb) {
  int q = blockIdx.x & 7, r = blockIdx.x >> 3;   // q -> XCD (perf heuristic only)
  if (q >= 4 || r >= 4) return;                  // 16 working blocks of 64
  int g = q, s = r;                              // group, column-slice
  int dir = g >> 1, half = g & 1;
  __shared__ u16 hl[16 * 512];                   // h for own batch-half, XOR-swizzled
  int tid = threadIdx.x, l = tid & 63, wn = tid >> 6;   // 8 waves = 8 n-tiles
  int arow = l & 15, kll = (l >> 4) << 3, lr = l >> 4, lc = l & 15;
  int sw = (arow & 7) << 3;
  int col0 = s * 128 + wn * 16 + lc;             // this lane's output column
  int ntg = s * 8 + wn;                          // global n-tile 0..31
  const u16* Up = dir ? Ubp : Ufp;
  const float* hid = dir ? hidden_b : hidden_f;
  float* st = dir ? state_b : state_f;
  int* fl = flags + g * 4;
  u16* xb0 = xb + (size_t)g * (16 * 512);
  u16* xb1 = xb + (size_t)(4 + g) * (16 * 512);

  half8 ub[16];                                  // U slice: register-resident
#pragma unroll
  for (int kt = 0; kt < 16; ++kt)
    ub[kt] = *(const half8*)(Up + ((size_t)(kt * 32 + ntg) * 64 + l) * 8);

  for (int e = tid; e < 16 * 512; e += 512) {
    int row = e >> 9, col = e & 511;
    hl[(row * 512 + col) ^ ((row & 7) << 3)] =
        f2h(hid[(size_t)(half * 16 + row) * 512 + col]);
  }
  u16 pxc[4], pxn[4];
  {
    int t0 = dir ? 511 : 0;
#pragma unroll
    for (int rr = 0; rr < 4; ++rr)
      pxc[rr] = xp[((size_t)(t0 * 2 + dir) * 32 + half * 16 + lr * 4 + rr) * 512 + col0];
  }
  __syncthreads();

  for (int i = 0; i < 512; ++i) {
    int t = dir ? (511 - i) : i;
    // prefetch next step's xp (latency hides under MFMA phase)
    if (i < 511) {
      int tn = dir ? (510 - i) : (i + 1);
#pragma unroll
      for (int rr = 0; rr < 4; ++rr)
        pxn[rr] = xp[((size_t)(tn * 2 + dir) * 32 + half * 16 + lr * 4 + rr) * 512 + col0];
    }
    // h_{i-1} @ U-slice : 16 MFMA, 2 interleaved acc chains
    f32x4 a0 = {}, a1 = {};
#pragma unroll
    for (int kt = 0; kt < 16; kt += 2) {
      half8 av0 = *(const half8*)(&hl[(arow * 512 + kt * 32 + kll) ^ sw]);
      a0 = __builtin_amdgcn_mfma_f32_16x16x32_f16(av0, ub[kt], a0, 0, 0, 0);
      half8 av1 = *(const half8*)(&hl[(arow * 512 + (kt + 1) * 32 + kll) ^ sw]);
      a1 = __builtin_amdgcn_mfma_f32_16x16x32_f16(av1, ub[kt + 1], a1, 0, 0, 0);
    }
    f32x4 acc = a0 + a1;
    u16* xbc = (i & 1) ? xb1 : xb0;
    float hv4[4];
#pragma unroll
    for (int rr = 0; rr < 4; ++rr) {
      float sv = acc[rr] + h2f(pxc[rr]);
      float hv = tanh_fast(sv);
      hv4[rr] = hv;
      int row_g = half * 16 + lr * 4 + rr;
      out[(size_t)row_g * (T_ * 1024) + (size_t)t * 1024 + dir * 512 + col0] = hv;
      if (i == 511) st[(size_t)row_g * 512 + col0] = hv;
    }
    if (i == 511) break;
#pragma unroll
    for (int rr = 0; rr < 4; ++rr)
      xbc[(lr * 4 + rr) * 512 + col0] = f2h(hv4[rr]);
    __syncthreads();   // drains vmcnt: all block's stores are in L2
    if (tid == 0)
      __hip_atomic_store(&fl[s], i + 1, __ATOMIC_RELEASE, __HIP_MEMORY_SCOPE_AGENT);
    // all waves spin on the group's 4 flags
    {
      int bail = 0;
      while (1) {
        int v = 0x7fffffff;
        if (l < 4) v = __hip_atomic_load(&fl[l], __ATOMIC_ACQUIRE, __HIP_MEMORY_SCOPE_AGENT);
        if (__all(v > i)) break;
        if (++bail > (1 << 22)) {          // safety net: fail, don't hang
          if (tid == 0)
            __hip_atomic_store(&fl[s], 0x40000000, __ATOMIC_RELEASE, __HIP_MEMORY_SCOPE_AGENT);
          return;
        }
      }
    }
    // gather full h_i (16x512) into LDS, swizzled
#pragma unroll
    for (int qq = 0; qq < 2; ++qq) {
      int e = (tid * 2 + qq) * 8;
      int row = e >> 9, c0 = e & 511;
      uint4 v = *(const uint4*)(xbc + row * 512 + c0);
      *(uint4*)(&hl[(row * 512 + c0) ^ ((row & 7) << 3)]) = v;
    }
#pragma unroll
    for (int rr = 0; rr < 4; ++rr) pxc[rr] = pxn[rr];
    __syncthreads();
  }
}

extern "C" void kernel_launch(void* const* d_in, const int* in_sizes, int n_in,
                              void* d_out, int out_size, void* d_ws, size_t ws_size,
                              hipStream_t stream) {
  const int* x = (const int*)d_in[0];
  const float* hidden_f = (const float*)d_in[1];
  const float* hidden_b = (const float*)d_in[2];
  const float* emb = (const float*)d_in[3];
  const float* Wf = (const float*)d_in[4];
  const float* Uf = (const float*)d_in[5];
  const float* bf = (const float*)d_in[6];
  const float* Wb = (const float*)d_in[7];
  const float* Ub = (const float*)d_in[8];
  const float* bb = (const float*)d_in[9];
  float* out = (float*)d_out;

  char* ws = (char*)d_ws;
  u16* Wp  = (u16*)(ws + OFF_WP);
  u16* Ufp = (u16*)(ws + OFF_UFP);
  u16* Ubp = (u16*)(ws + OFF_UBP);
  u16* Apk = (u16*)(ws + OFF_APK);
  u16* xpw = (u16*)(ws + OFF_XP);
  int* flags = (int*)(ws + OFF_FLAG);
  u16* xbuf = (u16*)(ws + OFF_XB);

  pack_WU<<<512, 256, 0, stream>>>(Wf, Wb, Uf, Ub, Wp, Ufp, Ubp);
  gather_pack_A<<<4096, 256, 0, stream>>>(x, emb, Apk);
  gemm_xp<<<1024, 256, 0, stream>>>(Apk, Wp, bf, bb, xpw);
  zero_flags<<<1, 16, 0, stream>>>(flags);   // Apk region is dead now; reuse
  rnn_scan2<<<64, 512, 0, stream>>>(xpw, Ufp, Ubp, hidden_f, hidden_b,
                                    out, out + OUT_ELEMS,
                                    out + OUT_ELEMS + (size_t)B_ * 512, flags, xbuf);
}

// Round 4
// 1584.498 us; speedup vs baseline: 1.8392x; 1.8392x over previous
//
#include <hip/hip_runtime.h>

typedef unsigned short u16;
typedef unsigned int u32;
typedef __attribute__((ext_vector_type(8))) _Float16 half8;
typedef __attribute__((ext_vector_type(4))) float f32x4;
typedef __attribute__((ext_vector_type(4))) u32 u32x4;

#define B_ 32
#define T_ 512
// ws layout (bytes)
#define OFF_WP   ((size_t)0)            // [kt16][nt64][lane64][j8] f16 : 1MB
#define OFF_UFP  ((size_t)1 << 20)      // [kt16][nt32][lane64][j8] f16 : 512KB
#define OFF_UBP  (((size_t)1 << 20) + ((size_t)512 << 10))
#define OFF_APK  ((size_t)2 << 20)      // A-frags for gemm : 16MB
#define OFF_XP   ((size_t)18 << 20)     // [t512][dir2][half2][tid512][e16] f16 : 32MB
#define OUT_ELEMS ((size_t)B_ * T_ * 1024)

__device__ __forceinline__ u16 f2h(float f) {
  _Float16 h = (_Float16)f; u16 r; __builtin_memcpy(&r, &h, 2); return r;
}
__device__ __forceinline__ float h2f(u16 b) {
  _Float16 h; __builtin_memcpy(&h, &b, 2); return (float)h;
}
__device__ __forceinline__ u32 pkh(float a, float b) {
  return (u32)f2h(a) | ((u32)f2h(b) << 16);
}
// fast tanh: 1 - 2/(e^{2x}+1); saturates correctly at +-inf
__device__ __forceinline__ float tanh_fast(float s) {
  float e2 = __expf(2.f * s);
  return 1.f - 2.f * __builtin_amdgcn_rcpf(e2 + 1.f);
}

// ---------------- P1: pack Wf|Wb (N=1024) and Uf, Ub (N=512) into B-frag order
// B-frag (16x16x32): lane l elem j -> B[kt*32 + (l>>4)*8 + j][nt*16 + (l&15)]
__global__ void pack_WU(const float* __restrict__ Wf, const float* __restrict__ Wb,
                        const float* __restrict__ Uf, const float* __restrict__ Ub,
                        u16* __restrict__ Wp, u16* __restrict__ Ufp, u16* __restrict__ Ubp) {
  int tid = blockIdx.x * 256 + threadIdx.x;  // 131072 total
  const float* src; u16* dst; int NT, k, n0;
  if (tid < 65536) {
    k = tid >> 7; n0 = (tid & 127) * 8;
    src = (n0 < 512) ? (Wf + (size_t)k * 512 + n0) : (Wb + (size_t)k * 512 + (n0 - 512));
    dst = Wp; NT = 64;
  } else if (tid < 98304) {
    int q = tid - 65536; k = q >> 6; n0 = (q & 63) * 8;
    src = Uf + (size_t)k * 512 + n0; dst = Ufp; NT = 32;
  } else {
    int q = tid - 98304; k = q >> 6; n0 = (q & 63) * 8;
    src = Ub + (size_t)k * 512 + n0; dst = Ubp; NT = 32;
  }
  float4 v0 = *(const float4*)src;
  float4 v1 = *(const float4*)(src + 4);
  float v[8] = {v0.x, v0.y, v0.z, v0.w, v1.x, v1.y, v1.z, v1.w};
  int kt = k >> 5, lhi = (k >> 3) & 3, jj = k & 7;
#pragma unroll
  for (int j = 0; j < 8; ++j) {
    int n = n0 + j, nt = n >> 4, llo = n & 15;
    dst[((size_t)(kt * NT + nt) * 64 + lhi * 16 + llo) * 8 + jj] = f2h(v[j]);
  }
}

// ---------------- P2: gather emb rows, convert f16, pack in A-frag order
__global__ void gather_pack_A(const int* __restrict__ x, const float* __restrict__ emb,
                              u16* __restrict__ Apk) {
  int tid = blockIdx.x * 256 + threadIdx.x;  // 1048576 total
  int l = tid & 63, kt = (tid >> 6) & 15, mt = tid >> 10;
  int m = mt * 16 + (l & 15);
  int tok = x[m];
  int k0 = kt * 32 + ((l >> 4) << 3);
  const float* src = emb + (size_t)tok * 512 + k0;
  float4 v0 = *(const float4*)src;
  float4 v1 = *(const float4*)(src + 4);
  uint4 o;
  o.x = pkh(v0.x, v0.y); o.y = pkh(v0.z, v0.w);
  o.z = pkh(v1.x, v1.y); o.w = pkh(v1.z, v1.w);
  *(uint4*)(Apk + (size_t)tid * 8) = o;
}

// ---------------- G: fragment-direct GEMM; epilogue writes xp in scan-thread order:
// xp[(((t*2+dir)*2 + half)*512 + scan_tid)*16 + (nt*4 + r)]
__launch_bounds__(256)
__global__ void gemm_xp(const u16* __restrict__ Apk, const u16* __restrict__ Wp,
                        const float* __restrict__ bf, const float* __restrict__ bb,
                        u16* __restrict__ xp) {
  int bid = blockIdx.x;            // 1024 = 128 (M) x 8 (N)
  int bm = bid >> 3, bn = bid & 7;
  int tid = threadIdx.x, l = tid & 63, wid = tid >> 6;
  int wm = wid >> 1, wn = wid & 1;
  int mt0 = bm * 8 + wm * 4;
  int nt0 = bn * 8 + wn * 4;
  const half8* Ap = (const half8*)Apk;
  const half8* Bp = (const half8*)Wp;
  f32x4 acc[4][4] = {};
#pragma unroll 2
  for (int kt = 0; kt < 16; ++kt) {
    half8 a[4], b[4];
#pragma unroll
    for (int i = 0; i < 4; ++i) a[i] = Ap[(size_t)((mt0 + i) * 16 + kt) * 64 + l];
#pragma unroll
    for (int j = 0; j < 4; ++j) b[j] = Bp[(size_t)(kt * 64 + nt0 + j) * 64 + l];
#pragma unroll
    for (int i = 0; i < 4; ++i)
#pragma unroll
      for (int j = 0; j < 4; ++j)
        acc[i][j] = __builtin_amdgcn_mfma_f32_16x16x32_f16(a[i], b[j], acc[i][j], 0, 0, 0);
  }
  int lr = l >> 4, lc = l & 15;
#pragma unroll
  for (int j = 0; j < 4; ++j) {
    int col = (nt0 + j) * 16 + lc;           // 0..1023
    int dirw = col >> 9, h = col & 511;
    float bias = dirw ? bb[h] : bf[h];
    int sw = h >> 6, snt = (h >> 4) & 3, slc = h & 15;
#pragma unroll
    for (int i2 = 0; i2 < 4; ++i2) {
#pragma unroll
      for (int r = 0; r < 4; ++r) {
        int m = (mt0 + i2) * 16 + lr * 4 + r;
        int b = m >> 9, t = m & 511;
        int halfb = (b >> 4) & 1, rb = b & 15;
        int slr = rb >> 2, sre = rb & 3;
        int stid = sw * 64 + slr * 16 + slc;
        int e = snt * 4 + sre;
        xp[(((size_t)(t * 2 + dirw) * 2 + halfb) * 512 + stid) * 16 + e] =
            f2h(acc[i2][j][r] + bias);
      }
    }
  }
}

// ---------------- R: 4 independent blocks (dir x batch-half), M=16, N=512.
// U per wave (4 ntiles x 16 kt): kt0-7 regs, kt8-11 LDS, kt12-15 loop-invariant regs.
// h single-buffered in LDS (16KB, XOR-swizzled), 2 barriers/step, no U streaming.
__launch_bounds__(512, 2)
__global__ void rnn_scan3(const u16* __restrict__ xp, const u16* __restrict__ Ufp,
                          const u16* __restrict__ Ubp, const float* __restrict__ hidden_f,
                          const float* __restrict__ hidden_b, float* __restrict__ out,
                          float* __restrict__ state_f, float* __restrict__ state_b) {
  __shared__ u16 hl[16 * 512];     // 16KB
  __shared__ u16 uls[128 * 512];   // 128KB: fid = ntg*4 + (kt-8); frag at fid*512 + l*8
  int tid = threadIdx.x, l = tid & 63, w = tid >> 6;
  int dir = blockIdx.x >> 1, half = blockIdx.x & 1;
  int b0 = half * 16;
  int lr = l >> 4, lc = l & 15;
  const u16* Up = dir ? Ubp : Ufp;
  const float* hid = dir ? hidden_b : hidden_f;
  float* st = dir ? state_b : state_f;

  // U kt0-7 -> regs
  half8 ub[4][8];
#pragma unroll
  for (int nt = 0; nt < 4; ++nt)
#pragma unroll
    for (int kt = 0; kt < 8; ++kt)
      ub[nt][kt] = *(const half8*)(Up + ((size_t)(kt * 32 + (w * 4 + nt)) * 64 + l) * 8);
  // U kt12-15 -> regs (loop-invariant)
  half8 sr[4][4];
#pragma unroll
  for (int nt = 0; nt < 4; ++nt)
#pragma unroll
    for (int j = 0; j < 4; ++j)
      sr[nt][j] = *(const half8*)(Up + ((size_t)((12 + j) * 32 + (w * 4 + nt)) * 64 + l) * 8);
  // U kt8-11 -> LDS (cooperative, 128 frags x 1KB)
  for (int idx = tid; idx < 128 * 64; idx += 512) {
    int fid = idx >> 6, lane = idx & 63;
    int ntg = fid >> 2, ku = (fid & 3) + 8;
    *(uint4*)(&uls[(size_t)fid * 512 + lane * 8]) =
        *(const uint4*)(Up + ((size_t)(ku * 32 + ntg) * 64 + lane) * 8);
  }
  // h init (f32 -> f16, swizzled)
  for (int e = tid; e < 16 * 512; e += 512) {
    int row = e >> 9, col = e & 511;
    hl[(row * 512 + col) ^ ((row & 7) << 3)] = f2h(hid[(size_t)(b0 + row) * 512 + col]);
  }
  __syncthreads();

  int arow = lc;                 // A-frag row = l&15
  int acolb = lr * 8;            // + kt*32
  int asw = (arow & 7) << 3;

  for (int i = 0; i < 512; ++i) {
    int t = dir ? (511 - i) : i;
    // xp for this step: 32B contiguous per thread (consumed in epilogue)
    const u32* xsrc = (const u32*)(xp + (((size_t)(t * 2 + dir) * 2 + half) * 512 + tid) * 16);
    u32x4 xv0 = __builtin_nontemporal_load((const u32x4*)xsrc);
    u32x4 xv1 = __builtin_nontemporal_load(((const u32x4*)xsrc) + 1);

    f32x4 acc[4] = {};
#pragma unroll
    for (int kt = 0; kt < 16; ++kt) {
      half8 a = *(const half8*)(&hl[(arow * 512 + kt * 32 + acolb) ^ asw]);
#pragma unroll
      for (int nt = 0; nt < 4; ++nt) {
        half8 b;
        if (kt < 8)       b = ub[nt][kt];
        else if (kt < 12) b = *(const half8*)(&uls[(size_t)((w * 4 + nt) * 4 + (kt - 8)) * 512 + l * 8]);
        else              b = sr[nt][kt - 12];
        acc[nt] = __builtin_amdgcn_mfma_f32_16x16x32_f16(a, b, acc[nt], 0, 0, 0);
      }
    }
    // epilogue: add xp (same f16 values as round-1 path), tanh, store out
    u16 xe[16];
    __builtin_memcpy(xe, &xv0, 16);
    __builtin_memcpy(xe + 8, &xv1, 16);
    u32 hvp[8];                       // packed f16 h_new (for LDS write after barrier)
#pragma unroll
    for (int nt = 0; nt < 4; ++nt) {
      int col = w * 64 + nt * 16 + lc;
      float hv[4];
#pragma unroll
      for (int r = 0; r < 4; ++r) {
        int e = nt * 4 + r;
        float sv = acc[nt][r] + h2f(xe[e]);
        hv[r] = tanh_fast(sv);
        int row = b0 + lr * 4 + r;
        __builtin_nontemporal_store(hv[r],
            out + ((size_t)row * 512 + t) * 1024 + dir * 512 + col);
        if (i == 511) st[(size_t)row * 512 + col] = hv[r];
      }
      hvp[nt * 2]     = pkh(hv[0], hv[1]);
      hvp[nt * 2 + 1] = pkh(hv[2], hv[3]);
    }
    __syncthreads();                 // all waves' A-reads of h_i done
    if (i < 511) {
#pragma unroll
      for (int nt = 0; nt < 4; ++nt) {
        int col = w * 64 + nt * 16 + lc;
#pragma unroll
        for (int r = 0; r < 4; ++r) {
          int row = lr * 4 + r;
          u16 hb = (u16)(hvp[nt * 2 + (r >> 1)] >> ((r & 1) * 16));
          hl[(row * 512 + col) ^ ((row & 7) << 3)] = hb;
        }
      }
      __syncthreads();               // h_{i+1} visible
    }
  }
}

extern "C" void kernel_launch(void* const* d_in, const int* in_sizes, int n_in,
                              void* d_out, int out_size, void* d_ws, size_t ws_size,
                              hipStream_t stream) {
  const int* x = (const int*)d_in[0];
  const float* hidden_f = (const float*)d_in[1];
  const float* hidden_b = (const float*)d_in[2];
  const float* emb = (const float*)d_in[3];
  const float* Wf = (const float*)d_in[4];
  const float* Uf = (const float*)d_in[5];
  const float* bf = (const float*)d_in[6];
  const float* Wb = (const float*)d_in[7];
  const float* Ub = (const float*)d_in[8];
  const float* bb = (const float*)d_in[9];
  float* out = (float*)d_out;

  char* ws = (char*)d_ws;
  u16* Wp  = (u16*)(ws + OFF_WP);
  u16* Ufp = (u16*)(ws + OFF_UFP);
  u16* Ubp = (u16*)(ws + OFF_UBP);
  u16* Apk = (u16*)(ws + OFF_APK);
  u16* xpw = (u16*)(ws + OFF_XP);

  pack_WU<<<512, 256, 0, stream>>>(Wf, Wb, Uf, Ub, Wp, Ufp, Ubp);
  gather_pack_A<<<4096, 256, 0, stream>>>(x, emb, Apk);
  gemm_xp<<<1024, 256, 0, stream>>>(Apk, Wp, bf, bb, xpw);
  rnn_scan3<<<4, 512, 0, stream>>>(xpw, Ufp, Ubp, hidden_f, hidden_b,
                                   out, out + OUT_ELEMS,
                                   out + OUT_ELEMS + (size_t)B_ * 512);
}